// Round 7
// baseline (195.216 us; speedup 1.0000x reference)
//
#include <hip/hip_runtime.h>
#include <hip/hip_bf16.h>
#include <math.h>

// ---------------------------------------------------------------------------
// GCN 2-layer forward. Pipeline:
//   1) zero: count=0, cursor=1 (slot 0 of each segment = self-loop)
//   2) histogram of dst (in-degree), x4 unrolled
//   3) parallel scan: bsum_k + scan2_k -> rd2 = {row_start, dinv} packed;
//      scan2 also seeds edata[row_start[v]] = {v, dinv^2} (self-loop, no atomic)
//   4) fill: CSR edata = {src, norm} grouped by dst, x4 independent chains
//   4b) wprep: W1^T -> bf16 hi/lo split
//   5) GEMM1 (MFMA): h1(bf16) = x @ W1 via 3-pass split bf16 (fp32-exact-ish)
//   6) AGG1: h = relu(gather-sum + b1), 16 lanes/node, x4 unroll
//   7) GEMM2: h2 = h @ W2
//   8) AGG2 + bias + log_softmax fused, x4 unroll
// ---------------------------------------------------------------------------

#define FIN 256
#define FH  128
#define FO  16
#define SCAN_CHUNK 1024

typedef unsigned int uint;
typedef unsigned short ushort;
typedef __attribute__((ext_vector_type(8))) short bf16x8;
typedef __attribute__((ext_vector_type(4))) float f32x4;

static __device__ __forceinline__ ushort f2bf(float f) {
    __hip_bfloat16 b = __float2bfloat16(f);
    return *reinterpret_cast<ushort*>(&b);
}
static __device__ __forceinline__ float bf2f(ushort u) {
    return __uint_as_float(((uint)u) << 16);
}

__global__ __launch_bounds__(256) void GCN_zero_k(int* __restrict__ count,
                                                  int* __restrict__ cursor, int N) {
    int i = blockIdx.x * 256 + threadIdx.x;
    if (i < N) { count[i] = 0; cursor[i] = 1; }
}

__global__ __launch_bounds__(256) void GCN_hist_k(const int* __restrict__ edge,
                                                  int* __restrict__ count, int E, int T) {
    int t = blockIdx.x * 256 + threadIdx.x;
    #pragma unroll
    for (int q = 0; q < 4; q++) {
        int i = t + q * T;
        if (i < E) atomicAdd(&count[edge[E + i]], 1);
    }
}

__global__ __launch_bounds__(256) void GCN_bsum_k(const int* __restrict__ count,
                                                  int* __restrict__ bsum, int N) {
    int tid = threadIdx.x;
    int i0 = blockIdx.x * SCAN_CHUNK + tid * 4;
    int s = 0;
    if (i0 + 3 < N) {
        int4 c = *(const int4*)&count[i0];
        s = c.x + c.y + c.z + c.w + 4;
    } else {
        for (int j = 0; j < 4; j++)
            if (i0 + j < N) s += count[i0 + j] + 1;
    }
    __shared__ int red[256];
    red[tid] = s;
    __syncthreads();
    for (int st = 128; st > 0; st >>= 1) {
        if (tid < st) red[tid] += red[tid + st];
        __syncthreads();
    }
    if (tid == 0) bsum[blockIdx.x] = red[0];
}

// scan2: rd2[v] = {row_start[v], bits(dinv[v])}; rd2[N].x = total;
// seeds self-loop entry edata[row_start[v]] = {v, dinv^2}.
__global__ __launch_bounds__(256) void GCN_scan2_k(const int* __restrict__ count,
                                                   const int* __restrict__ bsum,
                                                   int2* __restrict__ rd2,
                                                   int2* __restrict__ edata, int N) {
    int tid = threadIdx.x;
    int b = blockIdx.x;
    int i0 = b * SCAN_CHUNK + tid * 4;

    int v0 = 0, v1 = 0, v2 = 0, v3 = 0;
    if (i0 + 3 < N) {
        int4 c = *(const int4*)&count[i0];
        v0 = c.x + 1; v1 = c.y + 1; v2 = c.z + 1; v3 = c.w + 1;
    } else {
        if (i0 + 0 < N) v0 = count[i0 + 0] + 1;
        if (i0 + 1 < N) v1 = count[i0 + 1] + 1;
        if (i0 + 2 < N) v2 = count[i0 + 2] + 1;
        if (i0 + 3 < N) v3 = count[i0 + 3] + 1;
    }
    int lsum = v0 + v1 + v2 + v3;

    __shared__ int red[256];
    int offp = 0;
    for (int t = tid; t < b; t += 256) offp += bsum[t];
    red[tid] = offp;
    __syncthreads();
    for (int st = 128; st > 0; st >>= 1) {
        if (tid < st) red[tid] += red[tid + st];
        __syncthreads();
    }
    int blockOff = red[0];
    __syncthreads();

    __shared__ int ssum[256];
    ssum[tid] = lsum;
    __syncthreads();
    for (int off = 1; off < 256; off <<= 1) {
        int t = (tid >= off) ? ssum[tid - off] : 0;
        __syncthreads();
        ssum[tid] += t;
        __syncthreads();
    }
    int r = blockOff + (tid == 0 ? 0 : ssum[tid - 1]);

    #pragma unroll
    for (int q = 0; q < 4; q++) {
        int v = i0 + q;
        if (v < N) {
            int c = (q == 0) ? v0 : (q == 1) ? v1 : (q == 2) ? v2 : v3;
            float dv = rsqrtf((float)c);
            rd2[v] = make_int2(r, __float_as_int(dv));
            edata[r] = make_int2(v, __float_as_int(dv * dv));  // self-loop at slot 0
            r += c;
        }
    }
    if (b == gridDim.x - 1 && tid == 255) rd2[N] = make_int2(blockOff + ssum[255], 0);
}

// fill: 4 independent atomic chains per thread.
__global__ __launch_bounds__(256) void GCN_fill_k(const int* __restrict__ edge,
                                                  const int2* __restrict__ rd2,
                                                  int* __restrict__ cursor,
                                                  int2* __restrict__ edata,
                                                  int E, int T) {
    int t = blockIdx.x * 256 + threadIdx.x;
    int i0 = t, i1 = t + T, i2 = t + 2 * T, i3 = t + 3 * T;
    bool m0 = i0 < E, m1 = i1 < E, m2 = i2 < E, m3 = i3 < E;

    int s0 = 0, s1 = 0, s2 = 0, s3 = 0, d0 = 0, d1 = 0, d2 = 0, d3 = 0;
    if (m0) { s0 = edge[i0]; d0 = edge[E + i0]; }
    if (m1) { s1 = edge[i1]; d1 = edge[E + i1]; }
    if (m2) { s2 = edge[i2]; d2 = edge[E + i2]; }
    if (m3) { s3 = edge[i3]; d3 = edge[E + i3]; }

    int2 rdd0 = m0 ? rd2[d0] : make_int2(0, 0);
    int2 rdd1 = m1 ? rd2[d1] : make_int2(0, 0);
    int2 rdd2 = m2 ? rd2[d2] : make_int2(0, 0);
    int2 rdd3 = m3 ? rd2[d3] : make_int2(0, 0);
    float ds0 = m0 ? __int_as_float(rd2[s0].y) : 0.f;
    float ds1 = m1 ? __int_as_float(rd2[s1].y) : 0.f;
    float ds2 = m2 ? __int_as_float(rd2[s2].y) : 0.f;
    float ds3 = m3 ? __int_as_float(rd2[s3].y) : 0.f;

    int p0 = m0 ? atomicAdd(&cursor[d0], 1) : 0;
    int p1 = m1 ? atomicAdd(&cursor[d1], 1) : 0;
    int p2 = m2 ? atomicAdd(&cursor[d2], 1) : 0;
    int p3 = m3 ? atomicAdd(&cursor[d3], 1) : 0;

    if (m0) edata[rdd0.x + p0] = make_int2(s0, __float_as_int(ds0 * __int_as_float(rdd0.y)));
    if (m1) edata[rdd1.x + p1] = make_int2(s1, __float_as_int(ds1 * __int_as_float(rdd1.y)));
    if (m2) edata[rdd2.x + p2] = make_int2(s2, __float_as_int(ds2 * __int_as_float(rdd2.y)));
    if (m3) edata[rdd3.x + p3] = make_int2(s3, __float_as_int(ds3 * __int_as_float(rdd3.y)));
}

// W-prep: W1[256][128] fp32 -> whT/wlT [128 cols][256 k] bf16 hi/lo split.
__global__ __launch_bounds__(256) void GCN_wprep_k(const float* __restrict__ W1,
                                                   ushort* __restrict__ whT,
                                                   ushort* __restrict__ wlT) {
    int i = blockIdx.x * 256 + threadIdx.x;   // 32768
    int k = i >> 7, c = i & 127;
    float w = W1[i];
    ushort hh = f2bf(w);
    ushort hl = f2bf(w - bf2f(hh));
    whT[c * 256 + k] = hh;
    wlT[c * 256 + k] = hl;
}

// GEMM1 (MFMA): h1(bf16)[N][128] = x[N][256] @ W1[256][128]
#define G1_BR 64
#define G1_KC 64
__global__ __launch_bounds__(256, 2) void GCN_gemm1_k(const float* __restrict__ x,
                                                      const ushort* __restrict__ whT,
                                                      const ushort* __restrict__ wlT,
                                                      ushort* __restrict__ h1,
                                                      int N) {
    __shared__ __align__(16) ushort xh_s[G1_BR * G1_KC];
    __shared__ __align__(16) ushort xl_s[G1_BR * G1_KC];
    __shared__ __align__(16) ushort wh_s[FH * G1_KC];
    __shared__ __align__(16) ushort wl_s[FH * G1_KC];

    int tid = threadIdx.x;
    int row0 = blockIdx.x * G1_BR;
    int ln = tid & 63;
    int w  = tid >> 6;
    int ln15 = ln & 15;
    int q16  = ln >> 4;
    int sw   = (ln15 & 7) << 4;

    f32x4 acc[4][2];
    #pragma unroll
    for (int mr = 0; mr < 4; mr++)
        #pragma unroll
        for (int nc = 0; nc < 2; nc++) acc[mr][nc] = (f32x4){0.f, 0.f, 0.f, 0.f};

    for (int kc = 0; kc < FIN; kc += G1_KC) {
        #pragma unroll
        for (int j = 0; j < 4; j++) {
            int uu = tid + j * 256;
            int r = uu >> 4, kq = uu & 15;
            int gr = row0 + r;
            float4 v = make_float4(0.f, 0.f, 0.f, 0.f);
            if (gr < N) v = *(const float4*)&x[(size_t)gr * FIN + kc + kq * 4];
            ushort h0 = f2bf(v.x), h1v = f2bf(v.y), h2 = f2bf(v.z), h3 = f2bf(v.w);
            ushort l0 = f2bf(v.x - bf2f(h0));
            ushort l1 = f2bf(v.y - bf2f(h1v));
            ushort l2 = f2bf(v.z - bf2f(h2));
            ushort l3 = f2bf(v.w - bf2f(h3));
            uint2 hw, lw;
            hw.x = (uint)h0 | ((uint)h1v << 16);
            hw.y = (uint)h2 | ((uint)h3 << 16);
            lw.x = (uint)l0 | ((uint)l1 << 16);
            lw.y = (uint)l2 | ((uint)l3 << 16);
            int byte = (r * 128 + kq * 8) ^ ((r & 7) << 4);
            *(uint2*)((char*)xh_s + byte) = hw;
            *(uint2*)((char*)xl_s + byte) = lw;
        }
        #pragma unroll
        for (int j = 0; j < 4; j++) {
            int uu = tid + j * 256;
            int c = uu >> 3, ku = uu & 7;
            uint4 vh = *(const uint4*)&whT[(size_t)c * 256 + kc + ku * 8];
            uint4 vl = *(const uint4*)&wlT[(size_t)c * 256 + kc + ku * 8];
            int byte = (c * 128 + ku * 16) ^ ((c & 7) << 4);
            *(uint4*)((char*)wh_s + byte) = vh;
            *(uint4*)((char*)wl_s + byte) = vl;
        }
        __syncthreads();

        #pragma unroll
        for (int ks = 0; ks < 2; ks++) {
            int kk = (ks * 64 + q16 * 16) ^ sw;
            bf16x8 ah[4], al[4], bh[2], bl[2];
            #pragma unroll
            for (int mr = 0; mr < 4; mr++) {
                int r = mr * 16 + ln15;
                ah[mr] = *(const bf16x8*)((const char*)xh_s + r * 128 + kk);
                al[mr] = *(const bf16x8*)((const char*)xl_s + r * 128 + kk);
            }
            #pragma unroll
            for (int nc = 0; nc < 2; nc++) {
                int c = w * 32 + nc * 16 + ln15;
                bh[nc] = *(const bf16x8*)((const char*)wh_s + c * 128 + kk);
                bl[nc] = *(const bf16x8*)((const char*)wl_s + c * 128 + kk);
            }
            #pragma unroll
            for (int mr = 0; mr < 4; mr++)
                #pragma unroll
                for (int nc = 0; nc < 2; nc++) {
                    acc[mr][nc] = __builtin_amdgcn_mfma_f32_16x16x32_bf16(
                        ah[mr], bh[nc], acc[mr][nc], 0, 0, 0);
                    acc[mr][nc] = __builtin_amdgcn_mfma_f32_16x16x32_bf16(
                        al[mr], bh[nc], acc[mr][nc], 0, 0, 0);
                    acc[mr][nc] = __builtin_amdgcn_mfma_f32_16x16x32_bf16(
                        ah[mr], bl[nc], acc[mr][nc], 0, 0, 0);
                }
        }
        __syncthreads();
    }

    #pragma unroll
    for (int mr = 0; mr < 4; mr++) {
        #pragma unroll
        for (int nc = 0; nc < 2; nc++) {
            int cw = w * 32 + nc * 16 + ln15;
            #pragma unroll
            for (int j = 0; j < 4; j++) {
                int gr = row0 + mr * 16 + q16 * 4 + j;
                if (gr < N) h1[(size_t)gr * FH + cw] = f2bf(acc[mr][nc][j]);
            }
        }
    }
}

// AGG1: 16 lanes/node (8 bf16 each), edge loop unrolled x4.
__global__ __launch_bounds__(256) void GCN_agg1_k(const ushort* __restrict__ h1,
                                                  const int2* __restrict__ rd2,
                                                  const int2* __restrict__ ed,
                                                  const float* __restrict__ b1,
                                                  float* __restrict__ h, int N) {
    int gid = blockIdx.x * 256 + threadIdx.x;
    int node = gid >> 4;
    if (node >= N) return;
    int j = gid & 15;
    int beg = rd2[node].x, end = rd2[node + 1].x;
    const uint4* hp = (const uint4*)h1;

    float a[8];
    #pragma unroll
    for (int t = 0; t < 8; t++) a[t] = 0.f;

    int i = beg;
    for (; i + 4 <= end; i += 4) {
        int2 e0 = ed[i + 0], e1 = ed[i + 1], e2 = ed[i + 2], e3 = ed[i + 3];
        float w0 = __int_as_float(e0.y), w1 = __int_as_float(e1.y);
        float w2 = __int_as_float(e2.y), w3 = __int_as_float(e3.y);
        uint4 g0 = hp[(size_t)e0.x * 16 + j];
        uint4 g1 = hp[(size_t)e1.x * 16 + j];
        uint4 g2 = hp[(size_t)e2.x * 16 + j];
        uint4 g3 = hp[(size_t)e3.x * 16 + j];
        #pragma unroll
        for (int q = 0; q < 4; q++) {
            uint u0 = (&g0.x)[q], u1 = (&g1.x)[q], u2 = (&g2.x)[q], u3 = (&g3.x)[q];
            a[q*2+0] += __uint_as_float(u0 << 16) * w0;
            a[q*2+1] += __uint_as_float(u0 & 0xFFFF0000u) * w0;
            a[q*2+0] += __uint_as_float(u1 << 16) * w1;
            a[q*2+1] += __uint_as_float(u1 & 0xFFFF0000u) * w1;
            a[q*2+0] += __uint_as_float(u2 << 16) * w2;
            a[q*2+1] += __uint_as_float(u2 & 0xFFFF0000u) * w2;
            a[q*2+0] += __uint_as_float(u3 << 16) * w3;
            a[q*2+1] += __uint_as_float(u3 & 0xFFFF0000u) * w3;
        }
    }
    for (; i < end; i++) {
        int2 e = ed[i];
        float w = __int_as_float(e.y);
        uint4 g = hp[(size_t)e.x * 16 + j];
        #pragma unroll
        for (int q = 0; q < 4; q++) {
            uint u = (&g.x)[q];
            a[q*2+0] += __uint_as_float(u << 16) * w;
            a[q*2+1] += __uint_as_float(u & 0xFFFF0000u) * w;
        }
    }

    const float4* bp = (const float4*)b1;
    float4 bb0 = bp[j * 2 + 0];
    float4 bb1 = bp[j * 2 + 1];
    float4 o0, o1;
    o0.x = fmaxf(a[0] + bb0.x, 0.f);
    o0.y = fmaxf(a[1] + bb0.y, 0.f);
    o0.z = fmaxf(a[2] + bb0.z, 0.f);
    o0.w = fmaxf(a[3] + bb0.w, 0.f);
    o1.x = fmaxf(a[4] + bb1.x, 0.f);
    o1.y = fmaxf(a[5] + bb1.y, 0.f);
    o1.z = fmaxf(a[6] + bb1.z, 0.f);
    o1.w = fmaxf(a[7] + bb1.w, 0.f);
    float4* op = (float4*)h;
    op[(size_t)node * 32 + j * 2 + 0] = o0;
    op[(size_t)node * 32 + j * 2 + 1] = o1;
}

// GEMM2: h2[N][16] = h[N][128] @ W2[128][16].
__global__ __launch_bounds__(256) void GCN_gemm2_k(const float* __restrict__ h,
                                                   const float* __restrict__ W2,
                                                   float* __restrict__ h2, int N) {
    __shared__ float w2s[FH][FO];
    __shared__ float hs[16][FH + 4];
    int tid = threadIdx.x;
    #pragma unroll
    for (int j = 0; j < (FH * FO) / 256; j++) {
        int i = tid + j * 256;
        w2s[i >> 4][i & 15] = W2[i];
    }
    int row0 = blockIdx.x * 16;
    #pragma unroll
    for (int j = 0; j < (16 * FH) / 256; j++) {
        int i = tid + j * 256;
        int r = i >> 7, k = i & 127;
        int gr = row0 + r;
        hs[r][k] = (gr < N) ? h[gr * FH + k] : 0.f;
    }
    __syncthreads();
    int r = tid >> 4, f = tid & 15;
    float acc = 0.f;
    for (int k = 0; k < FH; k++) acc += hs[r][k] * w2s[k][f];
    int gr = row0 + r;
    if (gr < N) h2[gr * FO + f] = acc;
}

// AGG2 + bias + log_softmax fused. 16 lanes/node, x4 unroll.
__global__ __launch_bounds__(256) void GCN_agg2_k(const float* __restrict__ h2,
                                                  const int2* __restrict__ rd2,
                                                  const int2* __restrict__ ed,
                                                  const float* __restrict__ b2,
                                                  float* __restrict__ out, int N) {
    int tid = threadIdx.x;
    int node = blockIdx.x * 16 + (tid >> 4);
    if (node >= N) return;
    int f = tid & 15;
    int beg = rd2[node].x, end = rd2[node + 1].x;
    float acc = 0.f;
    int i = beg;
    for (; i + 4 <= end; i += 4) {
        int2 e0 = ed[i + 0], e1 = ed[i + 1], e2 = ed[i + 2], e3 = ed[i + 3];
        float g0 = h2[(size_t)e0.x * FO + f];
        float g1 = h2[(size_t)e1.x * FO + f];
        float g2 = h2[(size_t)e2.x * FO + f];
        float g3 = h2[(size_t)e3.x * FO + f];
        acc += g0 * __int_as_float(e0.y) + g1 * __int_as_float(e1.y)
             + g2 * __int_as_float(e2.y) + g3 * __int_as_float(e3.y);
    }
    for (; i < end; i++) {
        int2 e = ed[i];
        acc += h2[(size_t)e.x * FO + f] * __int_as_float(e.y);
    }
    float v = acc + b2[f];
    float mx = v;
    #pragma unroll
    for (int m = 8; m >= 1; m >>= 1) mx = fmaxf(mx, __shfl_xor(mx, m, 16));
    float e = expf(v - mx);
    float sum = e;
    #pragma unroll
    for (int m = 8; m >= 1; m >>= 1) sum += __shfl_xor(sum, m, 16);
    out[node * FO + f] = v - mx - logf(sum);
}

extern "C" void kernel_launch(void* const* d_in, const int* in_sizes, int n_in,
                              void* d_out, int out_size, void* d_ws, size_t ws_size,
                              hipStream_t stream) {
    (void)n_in; (void)out_size; (void)ws_size;
    const float* x  = (const float*)d_in[0];
    const int*   edp = (const int*)d_in[1];
    const float* W1 = (const float*)d_in[2];
    const float* b1 = (const float*)d_in[3];
    const float* W2 = (const float*)d_in[4];
    const float* b2 = (const float*)d_in[5];
    float* out = (float*)d_out;

    int N = in_sizes[0] / FIN;   // 50000
    int E = in_sizes[1] / 2;     // 800000
    int M = E + N;
    int nScanBlocks = (N + SCAN_CHUNK - 1) / SCAN_CHUNK;

    char* p = (char*)d_ws;
    auto take = [&](size_t bytes) -> char* {
        char* r = p;
        p += (bytes + 255) & ~(size_t)255;
        return r;
    };
    int*    count  = (int*)take((size_t)N * 4);
    int*    cursor = (int*)take((size_t)N * 4);
    int2*   rd2    = (int2*)take((size_t)(N + 1) * 8);
    int*    bsum   = (int*)take((size_t)nScanBlocks * 4);
    int2*   edata  = (int2*)take((size_t)M * 8);
    ushort* whT    = (ushort*)take((size_t)FH * FIN * 2);
    ushort* wlT    = (ushort*)take((size_t)FH * FIN * 2);
    ushort* h1     = (ushort*)take((size_t)N * FH * 2);
    float*  h      = (float*)take((size_t)N * FH * 4);
    float*  h2     = (float*)take((size_t)N * FO * 4);

    int fillT = ((E + 3) / 4 + 255) & ~255;       // threads for x4 unrolled kernels
    int fillBlocks = fillT / 256;

    GCN_zero_k<<<(N + 255) / 256, 256, 0, stream>>>(count, cursor, N);
    GCN_hist_k<<<fillBlocks, 256, 0, stream>>>(edp, count, E, fillT);
    GCN_bsum_k<<<nScanBlocks, 256, 0, stream>>>(count, bsum, N);
    GCN_scan2_k<<<nScanBlocks, 256, 0, stream>>>(count, bsum, rd2, edata, N);
    GCN_fill_k<<<fillBlocks, 256, 0, stream>>>(edp, rd2, cursor, edata, E, fillT);
    GCN_wprep_k<<<(FIN * FH) / 256, 256, 0, stream>>>(W1, whT, wlT);
    GCN_gemm1_k<<<(N + G1_BR - 1) / G1_BR, 256, 0, stream>>>(x, whT, wlT, h1, N);
    GCN_agg1_k<<<((size_t)N * 16 + 255) / 256, 256, 0, stream>>>(h1, rd2, edata, b1, h, N);
    GCN_gemm2_k<<<(N + 15) / 16, 256, 0, stream>>>(h, W2, h2, N);
    GCN_agg2_k<<<(N + 15) / 16, 256, 0, stream>>>(h2, rd2, edata, b2, out, N);
}

// Round 8
// 185.028 us; speedup vs baseline: 1.0551x; 1.0551x over previous
//
#include <hip/hip_runtime.h>
#include <hip/hip_bf16.h>
#include <math.h>

// ---------------------------------------------------------------------------
// GCN 2-layer forward. Pipeline:
//   1) zero: count=0, cursor=1 (slot 0 of each segment = self-loop)
//   2) histogram of dst (in-degree), 1 edge/thread
//   3) parallel scan: bsum_k + scan2_k -> rd2 = {row_start, dinv} packed;
//      scan2 seeds edata[row_start[v]] = {v, dinv^2} (self-loop, no atomic)
//   4) fill8: CSR edata = {src, norm}; dst-range x8 partitioned so each
//      edata/cursor region is written from (heuristically) one XCD ->
//      cache lines accumulate in one L2 instead of ping-ponging
//   4b) wprep: W1^T -> bf16 hi/lo split
//   5) GEMM1 (MFMA): h1(bf16) = x @ W1 via 3-pass split bf16 (fp32-exact-ish)
//   6) AGG1: h = relu(gather-sum + b1), 16 lanes/node, x4 unroll
//   7) GEMM2: h2 = h @ W2
//   8) AGG2 + bias + log_softmax fused, x4 unroll
// ---------------------------------------------------------------------------

#define FIN 256
#define FH  128
#define FO  16
#define SCAN_CHUNK 1024

typedef unsigned int uint;
typedef unsigned short ushort;
typedef __attribute__((ext_vector_type(8))) short bf16x8;
typedef __attribute__((ext_vector_type(4))) float f32x4;

static __device__ __forceinline__ ushort f2bf(float f) {
    __hip_bfloat16 b = __float2bfloat16(f);
    return *reinterpret_cast<ushort*>(&b);
}
static __device__ __forceinline__ float bf2f(ushort u) {
    return __uint_as_float(((uint)u) << 16);
}

__global__ __launch_bounds__(256) void GCN_zero_k(int* __restrict__ count,
                                                  int* __restrict__ cursor, int N) {
    int i = blockIdx.x * 256 + threadIdx.x;
    if (i < N) { count[i] = 0; cursor[i] = 1; }
}

__global__ __launch_bounds__(256) void GCN_hist_k(const int* __restrict__ edge,
                                                  int* __restrict__ count, int E) {
    int i = blockIdx.x * 256 + threadIdx.x;
    if (i < E) atomicAdd(&count[edge[E + i]], 1);
}

__global__ __launch_bounds__(256) void GCN_bsum_k(const int* __restrict__ count,
                                                  int* __restrict__ bsum, int N) {
    int tid = threadIdx.x;
    int i0 = blockIdx.x * SCAN_CHUNK + tid * 4;
    int s = 0;
    if (i0 + 3 < N) {
        int4 c = *(const int4*)&count[i0];
        s = c.x + c.y + c.z + c.w + 4;
    } else {
        for (int j = 0; j < 4; j++)
            if (i0 + j < N) s += count[i0 + j] + 1;
    }
    __shared__ int red[256];
    red[tid] = s;
    __syncthreads();
    for (int st = 128; st > 0; st >>= 1) {
        if (tid < st) red[tid] += red[tid + st];
        __syncthreads();
    }
    if (tid == 0) bsum[blockIdx.x] = red[0];
}

// scan2: rd2[v] = {row_start[v], bits(dinv[v])}; rd2[N].x = total;
// seeds self-loop entry edata[row_start[v]] = {v, dinv^2}.
__global__ __launch_bounds__(256) void GCN_scan2_k(const int* __restrict__ count,
                                                   const int* __restrict__ bsum,
                                                   int2* __restrict__ rd2,
                                                   int2* __restrict__ edata, int N) {
    int tid = threadIdx.x;
    int b = blockIdx.x;
    int i0 = b * SCAN_CHUNK + tid * 4;

    int v0 = 0, v1 = 0, v2 = 0, v3 = 0;
    if (i0 + 3 < N) {
        int4 c = *(const int4*)&count[i0];
        v0 = c.x + 1; v1 = c.y + 1; v2 = c.z + 1; v3 = c.w + 1;
    } else {
        if (i0 + 0 < N) v0 = count[i0 + 0] + 1;
        if (i0 + 1 < N) v1 = count[i0 + 1] + 1;
        if (i0 + 2 < N) v2 = count[i0 + 2] + 1;
        if (i0 + 3 < N) v3 = count[i0 + 3] + 1;
    }
    int lsum = v0 + v1 + v2 + v3;

    __shared__ int red[256];
    int offp = 0;
    for (int t = tid; t < b; t += 256) offp += bsum[t];
    red[tid] = offp;
    __syncthreads();
    for (int st = 128; st > 0; st >>= 1) {
        if (tid < st) red[tid] += red[tid + st];
        __syncthreads();
    }
    int blockOff = red[0];
    __syncthreads();

    __shared__ int ssum[256];
    ssum[tid] = lsum;
    __syncthreads();
    for (int off = 1; off < 256; off <<= 1) {
        int t = (tid >= off) ? ssum[tid - off] : 0;
        __syncthreads();
        ssum[tid] += t;
        __syncthreads();
    }
    int r = blockOff + (tid == 0 ? 0 : ssum[tid - 1]);

    #pragma unroll
    for (int q = 0; q < 4; q++) {
        int v = i0 + q;
        if (v < N) {
            int c = (q == 0) ? v0 : (q == 1) ? v1 : (q == 2) ? v2 : v3;
            float dv = rsqrtf((float)c);
            rd2[v] = make_int2(r, __float_as_int(dv));
            edata[r] = make_int2(v, __float_as_int(dv * dv));  // self-loop at slot 0
            r += c;
        }
    }
    if (b == gridDim.x - 1 && tid == 255) rd2[N] = make_int2(blockOff + ssum[255], 0);
}

// fill8: dst-range-partitioned counting-sort fill.
// Grid = 8 * nChunks. Block (chunk = bid>>3, range = bid&7) processes edges
// in its 256-edge chunk whose dst/qpr == range. All writes to a given
// edata/cursor region then come from blocks with the same (bid&7) -> same
// XCD under round-robin placement -> L2-local atomics + full-line writebacks.
__global__ __launch_bounds__(256) void GCN_fill_k(const int* __restrict__ edge,
                                                  const int2* __restrict__ rd2,
                                                  int* __restrict__ cursor,
                                                  int2* __restrict__ edata,
                                                  int E, int qpr) {
    int range = blockIdx.x & 7;
    int i = (blockIdx.x >> 3) * 256 + threadIdx.x;
    if (i >= E) return;
    int d = edge[E + i];
    if (d / qpr != range) return;
    int s = edge[i];
    int2 rdd = rd2[d];
    float ds = __int_as_float(rd2[s].y);
    int p = atomicAdd(&cursor[d], 1);
    edata[rdd.x + p] = make_int2(s, __float_as_int(ds * __int_as_float(rdd.y)));
}

// W-prep: W1[256][128] fp32 -> whT/wlT [128 cols][256 k] bf16 hi/lo split.
__global__ __launch_bounds__(256) void GCN_wprep_k(const float* __restrict__ W1,
                                                   ushort* __restrict__ whT,
                                                   ushort* __restrict__ wlT) {
    int i = blockIdx.x * 256 + threadIdx.x;   // 32768
    int k = i >> 7, c = i & 127;
    float w = W1[i];
    ushort hh = f2bf(w);
    ushort hl = f2bf(w - bf2f(hh));
    whT[c * 256 + k] = hh;
    wlT[c * 256 + k] = hl;
}

// GEMM1 (MFMA): h1(bf16)[N][128] = x[N][256] @ W1[256][128]
#define G1_BR 64
#define G1_KC 64
__global__ __launch_bounds__(256, 2) void GCN_gemm1_k(const float* __restrict__ x,
                                                      const ushort* __restrict__ whT,
                                                      const ushort* __restrict__ wlT,
                                                      ushort* __restrict__ h1,
                                                      int N) {
    __shared__ __align__(16) ushort xh_s[G1_BR * G1_KC];
    __shared__ __align__(16) ushort xl_s[G1_BR * G1_KC];
    __shared__ __align__(16) ushort wh_s[FH * G1_KC];
    __shared__ __align__(16) ushort wl_s[FH * G1_KC];

    int tid = threadIdx.x;
    int row0 = blockIdx.x * G1_BR;
    int ln = tid & 63;
    int w  = tid >> 6;
    int ln15 = ln & 15;
    int q16  = ln >> 4;
    int sw   = (ln15 & 7) << 4;

    f32x4 acc[4][2];
    #pragma unroll
    for (int mr = 0; mr < 4; mr++)
        #pragma unroll
        for (int nc = 0; nc < 2; nc++) acc[mr][nc] = (f32x4){0.f, 0.f, 0.f, 0.f};

    for (int kc = 0; kc < FIN; kc += G1_KC) {
        #pragma unroll
        for (int j = 0; j < 4; j++) {
            int uu = tid + j * 256;
            int r = uu >> 4, kq = uu & 15;
            int gr = row0 + r;
            float4 v = make_float4(0.f, 0.f, 0.f, 0.f);
            if (gr < N) v = *(const float4*)&x[(size_t)gr * FIN + kc + kq * 4];
            ushort h0 = f2bf(v.x), h1v = f2bf(v.y), h2 = f2bf(v.z), h3 = f2bf(v.w);
            ushort l0 = f2bf(v.x - bf2f(h0));
            ushort l1 = f2bf(v.y - bf2f(h1v));
            ushort l2 = f2bf(v.z - bf2f(h2));
            ushort l3 = f2bf(v.w - bf2f(h3));
            uint2 hw, lw;
            hw.x = (uint)h0 | ((uint)h1v << 16);
            hw.y = (uint)h2 | ((uint)h3 << 16);
            lw.x = (uint)l0 | ((uint)l1 << 16);
            lw.y = (uint)l2 | ((uint)l3 << 16);
            int byte = (r * 128 + kq * 8) ^ ((r & 7) << 4);
            *(uint2*)((char*)xh_s + byte) = hw;
            *(uint2*)((char*)xl_s + byte) = lw;
        }
        #pragma unroll
        for (int j = 0; j < 4; j++) {
            int uu = tid + j * 256;
            int c = uu >> 3, ku = uu & 7;
            uint4 vh = *(const uint4*)&whT[(size_t)c * 256 + kc + ku * 8];
            uint4 vl = *(const uint4*)&wlT[(size_t)c * 256 + kc + ku * 8];
            int byte = (c * 128 + ku * 16) ^ ((c & 7) << 4);
            *(uint4*)((char*)wh_s + byte) = vh;
            *(uint4*)((char*)wl_s + byte) = vl;
        }
        __syncthreads();

        #pragma unroll
        for (int ks = 0; ks < 2; ks++) {
            int kk = (ks * 64 + q16 * 16) ^ sw;
            bf16x8 ah[4], al[4], bh[2], bl[2];
            #pragma unroll
            for (int mr = 0; mr < 4; mr++) {
                int r = mr * 16 + ln15;
                ah[mr] = *(const bf16x8*)((const char*)xh_s + r * 128 + kk);
                al[mr] = *(const bf16x8*)((const char*)xl_s + r * 128 + kk);
            }
            #pragma unroll
            for (int nc = 0; nc < 2; nc++) {
                int c = w * 32 + nc * 16 + ln15;
                bh[nc] = *(const bf16x8*)((const char*)wh_s + c * 128 + kk);
                bl[nc] = *(const bf16x8*)((const char*)wl_s + c * 128 + kk);
            }
            #pragma unroll
            for (int mr = 0; mr < 4; mr++)
                #pragma unroll
                for (int nc = 0; nc < 2; nc++) {
                    acc[mr][nc] = __builtin_amdgcn_mfma_f32_16x16x32_bf16(
                        ah[mr], bh[nc], acc[mr][nc], 0, 0, 0);
                    acc[mr][nc] = __builtin_amdgcn_mfma_f32_16x16x32_bf16(
                        al[mr], bh[nc], acc[mr][nc], 0, 0, 0);
                    acc[mr][nc] = __builtin_amdgcn_mfma_f32_16x16x32_bf16(
                        ah[mr], bl[nc], acc[mr][nc], 0, 0, 0);
                }
        }
        __syncthreads();
    }

    #pragma unroll
    for (int mr = 0; mr < 4; mr++) {
        #pragma unroll
        for (int nc = 0; nc < 2; nc++) {
            int cw = w * 32 + nc * 16 + ln15;
            #pragma unroll
            for (int j = 0; j < 4; j++) {
                int gr = row0 + mr * 16 + q16 * 4 + j;
                if (gr < N) h1[(size_t)gr * FH + cw] = f2bf(acc[mr][nc][j]);
            }
        }
    }
}

// AGG1: 16 lanes/node (8 bf16 each), edge loop unrolled x4.
__global__ __launch_bounds__(256) void GCN_agg1_k(const ushort* __restrict__ h1,
                                                  const int2* __restrict__ rd2,
                                                  const int2* __restrict__ ed,
                                                  const float* __restrict__ b1,
                                                  float* __restrict__ h, int N) {
    int gid = blockIdx.x * 256 + threadIdx.x;
    int node = gid >> 4;
    if (node >= N) return;
    int j = gid & 15;
    int beg = rd2[node].x, end = rd2[node + 1].x;
    const uint4* hp = (const uint4*)h1;

    float a[8];
    #pragma unroll
    for (int t = 0; t < 8; t++) a[t] = 0.f;

    int i = beg;
    for (; i + 4 <= end; i += 4) {
        int2 e0 = ed[i + 0], e1 = ed[i + 1], e2 = ed[i + 2], e3 = ed[i + 3];
        float w0 = __int_as_float(e0.y), w1 = __int_as_float(e1.y);
        float w2 = __int_as_float(e2.y), w3 = __int_as_float(e3.y);
        uint4 g0 = hp[(size_t)e0.x * 16 + j];
        uint4 g1 = hp[(size_t)e1.x * 16 + j];
        uint4 g2 = hp[(size_t)e2.x * 16 + j];
        uint4 g3 = hp[(size_t)e3.x * 16 + j];
        #pragma unroll
        for (int q = 0; q < 4; q++) {
            uint u0 = (&g0.x)[q], u1 = (&g1.x)[q], u2 = (&g2.x)[q], u3 = (&g3.x)[q];
            a[q*2+0] += __uint_as_float(u0 << 16) * w0;
            a[q*2+1] += __uint_as_float(u0 & 0xFFFF0000u) * w0;
            a[q*2+0] += __uint_as_float(u1 << 16) * w1;
            a[q*2+1] += __uint_as_float(u1 & 0xFFFF0000u) * w1;
            a[q*2+0] += __uint_as_float(u2 << 16) * w2;
            a[q*2+1] += __uint_as_float(u2 & 0xFFFF0000u) * w2;
            a[q*2+0] += __uint_as_float(u3 << 16) * w3;
            a[q*2+1] += __uint_as_float(u3 & 0xFFFF0000u) * w3;
        }
    }
    for (; i < end; i++) {
        int2 e = ed[i];
        float w = __int_as_float(e.y);
        uint4 g = hp[(size_t)e.x * 16 + j];
        #pragma unroll
        for (int q = 0; q < 4; q++) {
            uint u = (&g.x)[q];
            a[q*2+0] += __uint_as_float(u << 16) * w;
            a[q*2+1] += __uint_as_float(u & 0xFFFF0000u) * w;
        }
    }

    const float4* bp = (const float4*)b1;
    float4 bb0 = bp[j * 2 + 0];
    float4 bb1 = bp[j * 2 + 1];
    float4 o0, o1;
    o0.x = fmaxf(a[0] + bb0.x, 0.f);
    o0.y = fmaxf(a[1] + bb0.y, 0.f);
    o0.z = fmaxf(a[2] + bb0.z, 0.f);
    o0.w = fmaxf(a[3] + bb0.w, 0.f);
    o1.x = fmaxf(a[4] + bb1.x, 0.f);
    o1.y = fmaxf(a[5] + bb1.y, 0.f);
    o1.z = fmaxf(a[6] + bb1.z, 0.f);
    o1.w = fmaxf(a[7] + bb1.w, 0.f);
    float4* op = (float4*)h;
    op[(size_t)node * 32 + j * 2 + 0] = o0;
    op[(size_t)node * 32 + j * 2 + 1] = o1;
}

// GEMM2: h2[N][16] = h[N][128] @ W2[128][16].
__global__ __launch_bounds__(256) void GCN_gemm2_k(const float* __restrict__ h,
                                                   const float* __restrict__ W2,
                                                   float* __restrict__ h2, int N) {
    __shared__ float w2s[FH][FO];
    __shared__ float hs[16][FH + 4];
    int tid = threadIdx.x;
    #pragma unroll
    for (int j = 0; j < (FH * FO) / 256; j++) {
        int i = tid + j * 256;
        w2s[i >> 4][i & 15] = W2[i];
    }
    int row0 = blockIdx.x * 16;
    #pragma unroll
    for (int j = 0; j < (16 * FH) / 256; j++) {
        int i = tid + j * 256;
        int r = i >> 7, k = i & 127;
        int gr = row0 + r;
        hs[r][k] = (gr < N) ? h[gr * FH + k] : 0.f;
    }
    __syncthreads();
    int r = tid >> 4, f = tid & 15;
    float acc = 0.f;
    for (int k = 0; k < FH; k++) acc += hs[r][k] * w2s[k][f];
    int gr = row0 + r;
    if (gr < N) h2[gr * FO + f] = acc;
}

// AGG2 + bias + log_softmax fused. 16 lanes/node, x4 unroll.
__global__ __launch_bounds__(256) void GCN_agg2_k(const float* __restrict__ h2,
                                                  const int2* __restrict__ rd2,
                                                  const int2* __restrict__ ed,
                                                  const float* __restrict__ b2,
                                                  float* __restrict__ out, int N) {
    int tid = threadIdx.x;
    int node = blockIdx.x * 16 + (tid >> 4);
    if (node >= N) return;
    int f = tid & 15;
    int beg = rd2[node].x, end = rd2[node + 1].x;
    float acc = 0.f;
    int i = beg;
    for (; i + 4 <= end; i += 4) {
        int2 e0 = ed[i + 0], e1 = ed[i + 1], e2 = ed[i + 2], e3 = ed[i + 3];
        float g0 = h2[(size_t)e0.x * FO + f];
        float g1 = h2[(size_t)e1.x * FO + f];
        float g2 = h2[(size_t)e2.x * FO + f];
        float g3 = h2[(size_t)e3.x * FO + f];
        acc += g0 * __int_as_float(e0.y) + g1 * __int_as_float(e1.y)
             + g2 * __int_as_float(e2.y) + g3 * __int_as_float(e3.y);
    }
    for (; i < end; i++) {
        int2 e = ed[i];
        acc += h2[(size_t)e.x * FO + f] * __int_as_float(e.y);
    }
    float v = acc + b2[f];
    float mx = v;
    #pragma unroll
    for (int m = 8; m >= 1; m >>= 1) mx = fmaxf(mx, __shfl_xor(mx, m, 16));
    float e = expf(v - mx);
    float sum = e;
    #pragma unroll
    for (int m = 8; m >= 1; m >>= 1) sum += __shfl_xor(sum, m, 16);
    out[node * FO + f] = v - mx - logf(sum);
}

extern "C" void kernel_launch(void* const* d_in, const int* in_sizes, int n_in,
                              void* d_out, int out_size, void* d_ws, size_t ws_size,
                              hipStream_t stream) {
    (void)n_in; (void)out_size; (void)ws_size;
    const float* x  = (const float*)d_in[0];
    const int*   edp = (const int*)d_in[1];
    const float* W1 = (const float*)d_in[2];
    const float* b1 = (const float*)d_in[3];
    const float* W2 = (const float*)d_in[4];
    const float* b2 = (const float*)d_in[5];
    float* out = (float*)d_out;

    int N = in_sizes[0] / FIN;   // 50000
    int E = in_sizes[1] / 2;     // 800000
    int M = E + N;
    int nScanBlocks = (N + SCAN_CHUNK - 1) / SCAN_CHUNK;
    int qpr = (N + 7) / 8;       // dst-range quota per partition

    char* p = (char*)d_ws;
    auto take = [&](size_t bytes) -> char* {
        char* r = p;
        p += (bytes + 255) & ~(size_t)255;
        return r;
    };
    int*    count  = (int*)take((size_t)N * 4);
    int*    cursor = (int*)take((size_t)N * 4);
    int2*   rd2    = (int2*)take((size_t)(N + 1) * 8);
    int*    bsum   = (int*)take((size_t)nScanBlocks * 4);
    int2*   edata  = (int2*)take((size_t)M * 8);
    ushort* whT    = (ushort*)take((size_t)FH * FIN * 2);
    ushort* wlT    = (ushort*)take((size_t)FH * FIN * 2);
    ushort* h1     = (ushort*)take((size_t)N * FH * 2);
    float*  h      = (float*)take((size_t)N * FH * 4);
    float*  h2     = (float*)take((size_t)N * FO * 4);

    int eBlocks = (E + 255) / 256;

    GCN_zero_k<<<(N + 255) / 256, 256, 0, stream>>>(count, cursor, N);
    GCN_hist_k<<<eBlocks, 256, 0, stream>>>(edp, count, E);
    GCN_bsum_k<<<nScanBlocks, 256, 0, stream>>>(count, bsum, N);
    GCN_scan2_k<<<nScanBlocks, 256, 0, stream>>>(count, bsum, rd2, edata, N);
    GCN_fill_k<<<eBlocks * 8, 256, 0, stream>>>(edp, rd2, cursor, edata, E, qpr);
    GCN_wprep_k<<<(FIN * FH) / 256, 256, 0, stream>>>(W1, whT, wlT);
    GCN_gemm1_k<<<(N + G1_BR - 1) / G1_BR, 256, 0, stream>>>(x, whT, wlT, h1, N);
    GCN_agg1_k<<<((size_t)N * 16 + 255) / 256, 256, 0, stream>>>(h1, rd2, edata, b1, h, N);
    GCN_gemm2_k<<<(N + 15) / 16, 256, 0, stream>>>(h, W2, h2, N);
    GCN_agg2_k<<<(N + 15) / 16, 256, 0, stream>>>(h2, rd2, edata, b2, out, N);
}

// Round 9
// 159.220 us; speedup vs baseline: 1.2261x; 1.1621x over previous
//
#include <hip/hip_runtime.h>
#include <hip/hip_bf16.h>
#include <math.h>

// ---------------------------------------------------------------------------
// GCN 2-layer forward. Pipeline:
//   1) zero: count=0, cursor=1 (slot 0 of each segment = self-loop)
//   2) histogram of dst (in-degree)
//   3) parallel scan: bsum_k + scan2_k -> rd2 = {row_start, dinv};
//      scan2 seeds edata[row_start[v]] = {v, dinv^2} (self-loop, no atomic)
//   4) wprep: W1^T -> bf16 hi/lo split
//   5) MEGA-A: blocks [0,nGemm) run GEMM1 (MFMA, KC=32, 3-pass split bf16);
//      remaining blocks run fill8 (dst-range-partitioned CSR scatter).
//      The latency-bound fill waves and MFMA-bound gemm waves co-schedule.
//   6) MEGA-B: agg1 (gather-sum + bias + relu, 16 lanes/node) -> h rows in
//      LDS -> gemm2 (h @ W2) fused; h never hits HBM.
//   7) AGG2 + bias + log_softmax fused, x4 unroll
// ---------------------------------------------------------------------------

#define FIN 256
#define FH  128
#define FO  16
#define SCAN_CHUNK 1024

typedef unsigned int uint;
typedef unsigned short ushort;
typedef __attribute__((ext_vector_type(8))) short bf16x8;
typedef __attribute__((ext_vector_type(4))) float f32x4;

static __device__ __forceinline__ ushort f2bf(float f) {
    __hip_bfloat16 b = __float2bfloat16(f);
    return *reinterpret_cast<ushort*>(&b);
}
static __device__ __forceinline__ float bf2f(ushort u) {
    return __uint_as_float(((uint)u) << 16);
}

__global__ __launch_bounds__(256) void GCN_zero_k(int* __restrict__ count,
                                                  int* __restrict__ cursor, int N) {
    int i = blockIdx.x * 256 + threadIdx.x;
    if (i < N) { count[i] = 0; cursor[i] = 1; }
}

__global__ __launch_bounds__(256) void GCN_hist_k(const int* __restrict__ edge,
                                                  int* __restrict__ count, int E) {
    int i = blockIdx.x * 256 + threadIdx.x;
    if (i < E) atomicAdd(&count[edge[E + i]], 1);
}

__global__ __launch_bounds__(256) void GCN_bsum_k(const int* __restrict__ count,
                                                  int* __restrict__ bsum, int N) {
    int tid = threadIdx.x;
    int i0 = blockIdx.x * SCAN_CHUNK + tid * 4;
    int s = 0;
    if (i0 + 3 < N) {
        int4 c = *(const int4*)&count[i0];
        s = c.x + c.y + c.z + c.w + 4;
    } else {
        for (int j = 0; j < 4; j++)
            if (i0 + j < N) s += count[i0 + j] + 1;
    }
    __shared__ int red[256];
    red[tid] = s;
    __syncthreads();
    for (int st = 128; st > 0; st >>= 1) {
        if (tid < st) red[tid] += red[tid + st];
        __syncthreads();
    }
    if (tid == 0) bsum[blockIdx.x] = red[0];
}

// scan2: rd2[v] = {row_start[v], bits(dinv[v])}; rd2[N].x = total;
// seeds self-loop entry edata[row_start[v]] = {v, dinv^2}.
__global__ __launch_bounds__(256) void GCN_scan2_k(const int* __restrict__ count,
                                                   const int* __restrict__ bsum,
                                                   int2* __restrict__ rd2,
                                                   int2* __restrict__ edata, int N) {
    int tid = threadIdx.x;
    int b = blockIdx.x;
    int i0 = b * SCAN_CHUNK + tid * 4;

    int v0 = 0, v1 = 0, v2 = 0, v3 = 0;
    if (i0 + 3 < N) {
        int4 c = *(const int4*)&count[i0];
        v0 = c.x + 1; v1 = c.y + 1; v2 = c.z + 1; v3 = c.w + 1;
    } else {
        if (i0 + 0 < N) v0 = count[i0 + 0] + 1;
        if (i0 + 1 < N) v1 = count[i0 + 1] + 1;
        if (i0 + 2 < N) v2 = count[i0 + 2] + 1;
        if (i0 + 3 < N) v3 = count[i0 + 3] + 1;
    }
    int lsum = v0 + v1 + v2 + v3;

    __shared__ int red[256];
    int offp = 0;
    for (int t = tid; t < b; t += 256) offp += bsum[t];
    red[tid] = offp;
    __syncthreads();
    for (int st = 128; st > 0; st >>= 1) {
        if (tid < st) red[tid] += red[tid + st];
        __syncthreads();
    }
    int blockOff = red[0];
    __syncthreads();

    __shared__ int ssum[256];
    ssum[tid] = lsum;
    __syncthreads();
    for (int off = 1; off < 256; off <<= 1) {
        int t = (tid >= off) ? ssum[tid - off] : 0;
        __syncthreads();
        ssum[tid] += t;
        __syncthreads();
    }
    int r = blockOff + (tid == 0 ? 0 : ssum[tid - 1]);

    #pragma unroll
    for (int q = 0; q < 4; q++) {
        int v = i0 + q;
        if (v < N) {
            int c = (q == 0) ? v0 : (q == 1) ? v1 : (q == 2) ? v2 : v3;
            float dv = rsqrtf((float)c);
            rd2[v] = make_int2(r, __float_as_int(dv));
            edata[r] = make_int2(v, __float_as_int(dv * dv));  // self-loop at slot 0
            r += c;
        }
    }
    if (b == gridDim.x - 1 && tid == 255) rd2[N] = make_int2(blockOff + ssum[255], 0);
}

// W-prep: W1[256][128] fp32 -> whT/wlT [128 cols][256 k] bf16 hi/lo split.
__global__ __launch_bounds__(256) void GCN_wprep_k(const float* __restrict__ W1,
                                                   ushort* __restrict__ whT,
                                                   ushort* __restrict__ wlT) {
    int i = blockIdx.x * 256 + threadIdx.x;   // 32768
    int k = i >> 7, c = i & 127;
    float w = W1[i];
    ushort hh = f2bf(w);
    ushort hl = f2bf(w - bf2f(hh));
    whT[c * 256 + k] = hh;
    wlT[c * 256 + k] = hl;
}

// MEGA-A: blocks [0,nGemm) = GEMM1; blocks [nGemm, nGemm+8*eBlocks) = fill8.
// GEMM1: h1(bf16)[N][128] = x @ W1. 4 waves, tile 64x128, KC=32. 3-pass
// split-bf16 MFMA. LDS rows 64B, swizzle byte^=((r>>1)&3)<<4 -> even spread.
// fill8: dst-range x8 partitioned counting-sort scatter (XCD-local cursor).
#define G1_BR 64
#define G1_KC 32
__global__ __launch_bounds__(256, 4) void GCN_fillgemm_k(
        const float* __restrict__ x, const ushort* __restrict__ whT,
        const ushort* __restrict__ wlT, ushort* __restrict__ h1,
        const int* __restrict__ edge, const int2* __restrict__ rd2,
        int* __restrict__ cursor, int2* __restrict__ edata,
        int N, int E, int qpr, int nGemm) {
    __shared__ __align__(16) ushort xh_s[G1_BR * G1_KC];   // 4 KiB
    __shared__ __align__(16) ushort xl_s[G1_BR * G1_KC];   // 4 KiB
    __shared__ __align__(16) ushort wh_s[FH * G1_KC];      // 8 KiB
    __shared__ __align__(16) ushort wl_s[FH * G1_KC];      // 8 KiB
    int tid = threadIdx.x;

    if (blockIdx.x >= nGemm) {
        // ---- fill path ----
        int bid = blockIdx.x - nGemm;
        int range = bid & 7;
        int i = (bid >> 3) * 256 + tid;
        if (i < E) {
            int d = edge[E + i];
            if (d / qpr == range) {
                int s = edge[i];
                int2 rdd = rd2[d];
                float ds = __int_as_float(rd2[s].y);
                int p = atomicAdd(&cursor[d], 1);
                edata[rdd.x + p] =
                    make_int2(s, __float_as_int(ds * __int_as_float(rdd.y)));
            }
        }
        return;
    }

    // ---- gemm1 path ----
    int row0 = blockIdx.x * G1_BR;
    int ln = tid & 63;
    int w  = tid >> 6;          // wave 0..3 -> col slab w*32
    int ln15 = ln & 15;
    int q16  = ln >> 4;         // k-slot 0..3

    f32x4 acc[4][2];
    #pragma unroll
    for (int mr = 0; mr < 4; mr++)
        #pragma unroll
        for (int nc = 0; nc < 2; nc++) acc[mr][nc] = (f32x4){0.f, 0.f, 0.f, 0.f};

    for (int kc = 0; kc < FIN; kc += G1_KC) {
        // stage x tile [64r][32k]: 512 float4 / 256 thr = 2 each
        #pragma unroll
        for (int j = 0; j < 2; j++) {
            int u = tid + j * 256;
            int r = u >> 3, kq = u & 7;       // 8 float4 per row
            int gr = row0 + r;
            float4 v = make_float4(0.f, 0.f, 0.f, 0.f);
            if (gr < N) v = *(const float4*)&x[(size_t)gr * FIN + kc + kq * 4];
            ushort h0 = f2bf(v.x), h1v = f2bf(v.y), h2 = f2bf(v.z), h3 = f2bf(v.w);
            ushort l0 = f2bf(v.x - bf2f(h0));
            ushort l1 = f2bf(v.y - bf2f(h1v));
            ushort l2 = f2bf(v.z - bf2f(h2));
            ushort l3 = f2bf(v.w - bf2f(h3));
            uint2 hw, lw;
            hw.x = (uint)h0 | ((uint)h1v << 16);
            hw.y = (uint)h2 | ((uint)h3 << 16);
            lw.x = (uint)l0 | ((uint)l1 << 16);
            lw.y = (uint)l2 | ((uint)l3 << 16);
            int byte = (r * 64 + kq * 8) ^ (((r >> 1) & 3) << 4);
            *(uint2*)((char*)xh_s + byte) = hw;
            *(uint2*)((char*)xl_s + byte) = lw;
        }
        // stage W tiles [128c][32k]: 512 uint4 / 256 thr = 2 each
        #pragma unroll
        for (int j = 0; j < 2; j++) {
            int u = tid + j * 256;
            int c = u >> 2, ku = u & 3;       // 4 x 16B per col
            uint4 vh = *(const uint4*)&whT[(size_t)c * 256 + kc + ku * 8];
            uint4 vl = *(const uint4*)&wlT[(size_t)c * 256 + kc + ku * 8];
            int byte = (c * 64 + ku * 16) ^ (((c >> 1) & 3) << 4);
            *(uint4*)((char*)wh_s + byte) = vh;
            *(uint4*)((char*)wl_s + byte) = vl;
        }
        __syncthreads();

        bf16x8 ah[4], al[4], bh[2], bl[2];
        #pragma unroll
        for (int mr = 0; mr < 4; mr++) {
            int r = mr * 16 + ln15;
            int byte = r * 64 + ((q16 * 16) ^ (((r >> 1) & 3) << 4));
            ah[mr] = *(const bf16x8*)((const char*)xh_s + byte);
            al[mr] = *(const bf16x8*)((const char*)xl_s + byte);
        }
        #pragma unroll
        for (int nc = 0; nc < 2; nc++) {
            int c = w * 32 + nc * 16 + ln15;
            int byte = c * 64 + ((q16 * 16) ^ (((c >> 1) & 3) << 4));
            bh[nc] = *(const bf16x8*)((const char*)wh_s + byte);
            bl[nc] = *(const bf16x8*)((const char*)wl_s + byte);
        }
        #pragma unroll
        for (int mr = 0; mr < 4; mr++)
            #pragma unroll
            for (int nc = 0; nc < 2; nc++) {
                acc[mr][nc] = __builtin_amdgcn_mfma_f32_16x16x32_bf16(
                    ah[mr], bh[nc], acc[mr][nc], 0, 0, 0);
                acc[mr][nc] = __builtin_amdgcn_mfma_f32_16x16x32_bf16(
                    al[mr], bh[nc], acc[mr][nc], 0, 0, 0);
                acc[mr][nc] = __builtin_amdgcn_mfma_f32_16x16x32_bf16(
                    ah[mr], bl[nc], acc[mr][nc], 0, 0, 0);
            }
        __syncthreads();
    }

    // epilogue: D layout col=lane&15, row=(lane>>4)*4+reg  [m89-verified]
    #pragma unroll
    for (int mr = 0; mr < 4; mr++) {
        #pragma unroll
        for (int nc = 0; nc < 2; nc++) {
            int cw = w * 32 + nc * 16 + ln15;
            #pragma unroll
            for (int j = 0; j < 4; j++) {
                int gr = row0 + mr * 16 + q16 * 4 + j;
                if (gr < N) h1[(size_t)gr * FH + cw] = f2bf(acc[mr][nc][j]);
            }
        }
    }
}

// MEGA-B: agg1 (16 lanes/node, x4 unroll) -> h rows in LDS -> gemm2 fused.
// Block = 256 thr = 16 nodes; N % 16 == 0 for this problem (guards kept).
__global__ __launch_bounds__(256) void GCN_agg1gemm2_k(
        const ushort* __restrict__ h1, const int2* __restrict__ rd2,
        const int2* __restrict__ ed, const float* __restrict__ b1,
        const float* __restrict__ W2, float* __restrict__ h2, int N) {
    __shared__ float w2s[FH][FO];        // 8 KiB
    __shared__ float hs[16][FH + 4];     // 8.25 KiB
    int tid = threadIdx.x;
    // stage W2 (8 floats per thread)
    #pragma unroll
    for (int j = 0; j < (FH * FO) / 256; j++) {
        int i = tid + j * 256;
        w2s[i >> 4][i & 15] = W2[i];
    }

    int node0 = blockIdx.x * 16;
    int local = tid >> 4;
    int j = tid & 15;             // 16B unit: cols 8j..8j+7
    int node = node0 + local;

    if (node < N) {
        int beg = rd2[node].x, end = rd2[node + 1].x;
        const uint4* hp = (const uint4*)h1;

        float a[8];
        #pragma unroll
        for (int t = 0; t < 8; t++) a[t] = 0.f;

        int i = beg;
        for (; i + 4 <= end; i += 4) {
            int2 e0 = ed[i + 0], e1 = ed[i + 1], e2 = ed[i + 2], e3 = ed[i + 3];
            float w0 = __int_as_float(e0.y), w1 = __int_as_float(e1.y);
            float w2 = __int_as_float(e2.y), w3 = __int_as_float(e3.y);
            uint4 g0 = hp[(size_t)e0.x * 16 + j];
            uint4 g1 = hp[(size_t)e1.x * 16 + j];
            uint4 g2 = hp[(size_t)e2.x * 16 + j];
            uint4 g3 = hp[(size_t)e3.x * 16 + j];
            #pragma unroll
            for (int q = 0; q < 4; q++) {
                uint u0 = (&g0.x)[q], u1 = (&g1.x)[q], u2 = (&g2.x)[q], u3 = (&g3.x)[q];
                a[q*2+0] += __uint_as_float(u0 << 16) * w0;
                a[q*2+1] += __uint_as_float(u0 & 0xFFFF0000u) * w0;
                a[q*2+0] += __uint_as_float(u1 << 16) * w1;
                a[q*2+1] += __uint_as_float(u1 & 0xFFFF0000u) * w1;
                a[q*2+0] += __uint_as_float(u2 << 16) * w2;
                a[q*2+1] += __uint_as_float(u2 & 0xFFFF0000u) * w2;
                a[q*2+0] += __uint_as_float(u3 << 16) * w3;
                a[q*2+1] += __uint_as_float(u3 & 0xFFFF0000u) * w3;
            }
        }
        for (; i < end; i++) {
            int2 e = ed[i];
            float w = __int_as_float(e.y);
            uint4 g = hp[(size_t)e.x * 16 + j];
            #pragma unroll
            for (int q = 0; q < 4; q++) {
                uint u = (&g.x)[q];
                a[q*2+0] += __uint_as_float(u << 16) * w;
                a[q*2+1] += __uint_as_float(u & 0xFFFF0000u) * w;
            }
        }

        const float4* bp = (const float4*)b1;
        float4 bb0 = bp[j * 2 + 0];
        float4 bb1 = bp[j * 2 + 1];
        float4 o0, o1;
        o0.x = fmaxf(a[0] + bb0.x, 0.f);
        o0.y = fmaxf(a[1] + bb0.y, 0.f);
        o0.z = fmaxf(a[2] + bb0.z, 0.f);
        o0.w = fmaxf(a[3] + bb0.w, 0.f);
        o1.x = fmaxf(a[4] + bb1.x, 0.f);
        o1.y = fmaxf(a[5] + bb1.y, 0.f);
        o1.z = fmaxf(a[6] + bb1.z, 0.f);
        o1.w = fmaxf(a[7] + bb1.w, 0.f);
        *(float4*)&hs[local][j * 8 + 0] = o0;
        *(float4*)&hs[local][j * 8 + 4] = o1;
    }
    __syncthreads();

    // gemm2 from LDS: thread (r=local, f=j)
    float acc = 0.f;
    #pragma unroll 8
    for (int k = 0; k < FH; k++) acc += hs[local][k] * w2s[k][j];
    if (node < N) h2[(size_t)node * FO + j] = acc;
}

// AGG2 + bias + log_softmax fused. 16 lanes/node, x4 unroll.
__global__ __launch_bounds__(256) void GCN_agg2_k(const float* __restrict__ h2,
                                                  const int2* __restrict__ rd2,
                                                  const int2* __restrict__ ed,
                                                  const float* __restrict__ b2,
                                                  float* __restrict__ out, int N) {
    int tid = threadIdx.x;
    int node = blockIdx.x * 16 + (tid >> 4);
    if (node >= N) return;
    int f = tid & 15;
    int beg = rd2[node].x, end = rd2[node + 1].x;
    float acc = 0.f;
    int i = beg;
    for (; i + 4 <= end; i += 4) {
        int2 e0 = ed[i + 0], e1 = ed[i + 1], e2 = ed[i + 2], e3 = ed[i + 3];
        float g0 = h2[(size_t)e0.x * FO + f];
        float g1 = h2[(size_t)e1.x * FO + f];
        float g2 = h2[(size_t)e2.x * FO + f];
        float g3 = h2[(size_t)e3.x * FO + f];
        acc += g0 * __int_as_float(e0.y) + g1 * __int_as_float(e1.y)
             + g2 * __int_as_float(e2.y) + g3 * __int_as_float(e3.y);
    }
    for (; i < end; i++) {
        int2 e = ed[i];
        acc += h2[(size_t)e.x * FO + f] * __int_as_float(e.y);
    }
    float v = acc + b2[f];
    float mx = v;
    #pragma unroll
    for (int m = 8; m >= 1; m >>= 1) mx = fmaxf(mx, __shfl_xor(mx, m, 16));
    float e = expf(v - mx);
    float sum = e;
    #pragma unroll
    for (int m = 8; m >= 1; m >>= 1) sum += __shfl_xor(sum, m, 16);
    out[node * FO + f] = v - mx - logf(sum);
}

extern "C" void kernel_launch(void* const* d_in, const int* in_sizes, int n_in,
                              void* d_out, int out_size, void* d_ws, size_t ws_size,
                              hipStream_t stream) {
    (void)n_in; (void)out_size; (void)ws_size;
    const float* x  = (const float*)d_in[0];
    const int*   edp = (const int*)d_in[1];
    const float* W1 = (const float*)d_in[2];
    const float* b1 = (const float*)d_in[3];
    const float* W2 = (const float*)d_in[4];
    const float* b2 = (const float*)d_in[5];
    float* out = (float*)d_out;

    int N = in_sizes[0] / FIN;   // 50000
    int E = in_sizes[1] / 2;     // 800000
    int M = E + N;
    int nScanBlocks = (N + SCAN_CHUNK - 1) / SCAN_CHUNK;
    int qpr = (N + 7) / 8;       // dst-range quota per partition

    char* p = (char*)d_ws;
    auto take = [&](size_t bytes) -> char* {
        char* r = p;
        p += (bytes + 255) & ~(size_t)255;
        return r;
    };
    int*    count  = (int*)take((size_t)N * 4);
    int*    cursor = (int*)take((size_t)N * 4);
    int2*   rd2    = (int2*)take((size_t)(N + 1) * 8);
    int*    bsum   = (int*)take((size_t)nScanBlocks * 4);
    int2*   edata  = (int2*)take((size_t)M * 8);
    ushort* whT    = (ushort*)take((size_t)FH * FIN * 2);
    ushort* wlT    = (ushort*)take((size_t)FH * FIN * 2);
    ushort* h1     = (ushort*)take((size_t)N * FH * 2);
    float*  h2     = (float*)take((size_t)N * FO * 4);

    int eBlocks = (E + 255) / 256;            // 3125 (E divisible by 256)
    int nGemm   = (N + G1_BR - 1) / G1_BR;    // 782

    GCN_zero_k<<<(N + 255) / 256, 256, 0, stream>>>(count, cursor, N);
    GCN_hist_k<<<eBlocks, 256, 0, stream>>>(edp, count, E);
    GCN_bsum_k<<<nScanBlocks, 256, 0, stream>>>(count, bsum, N);
    GCN_scan2_k<<<nScanBlocks, 256, 0, stream>>>(count, bsum, rd2, edata, N);
    GCN_wprep_k<<<(FIN * FH) / 256, 256, 0, stream>>>(W1, whT, wlT);
    GCN_fillgemm_k<<<nGemm + eBlocks * 8, 256, 0, stream>>>(
        x, whT, wlT, h1, edp, rd2, cursor, edata, N, E, qpr, nGemm);
    GCN_agg1gemm2_k<<<(N + 15) / 16, 256, 0, stream>>>(h1, rd2, edata, b1, W2, h2, N);
    GCN_agg2_k<<<(N + 15) / 16, 256, 0, stream>>>(h2, rd2, edata, b2, out, N);
}